// Round 3
// baseline (1385.288 us; speedup 1.0000x reference)
//
#include <hip/hip_runtime.h>
#include <stdint.h>

__host__ __device__ inline void tf2x32(uint32_t k0, uint32_t k1,
                                       uint32_t x0, uint32_t x1,
                                       uint32_t* o0, uint32_t* o1) {
  const uint32_t ks2 = k0 ^ k1 ^ 0x1BD11BDAu;
#define ROTL(v, s) (((v) << (s)) | ((v) >> (32 - (s))))
#define RND(r) do { x0 += x1; x1 = ROTL(x1, r); x1 ^= x0; } while (0)
  x0 += k0; x1 += k1;
  RND(13); RND(15); RND(26); RND(6);
  x0 += k1; x1 += ks2 + 1u;
  RND(17); RND(29); RND(16); RND(24);
  x0 += ks2; x1 += k0 + 2u;
  RND(13); RND(15); RND(26); RND(6);
  x0 += k0; x1 += k1 + 3u;
  RND(17); RND(29); RND(16); RND(24);
  x0 += k1; x1 += ks2 + 4u;
  RND(13); RND(15); RND(26); RND(6);
  x0 += ks2; x1 += k0 + 5u;
  *o0 = x0; *o1 = x1;
#undef RND
#undef ROTL
}

__device__ inline bool drop_keep(uint32_t k0, uint32_t k1, uint32_t idx) {
  uint32_t o0, o1;
  tf2x32(k0, k1, 0u, idx, &o0, &o1);
  uint32_t bits = o0 ^ o1;
  float u = __uint_as_float((bits >> 9) | 0x3f800000u) - 1.0f;
  return u < 0.4f;
}

__global__ void k_deg(const int* __restrict__ row, int* __restrict__ deg, int e) {
  int i = blockIdx.x * 256 + threadIdx.x;
  if (i < e) atomicAdd(&deg[row[i]], 1);
}

__global__ void k_scan_block(const int* __restrict__ deg, int* __restrict__ rp,
                             int* __restrict__ blksum, int n) {
  __shared__ int sm[256];
  int i = blockIdx.x * 256 + threadIdx.x;
  int v = (i < n) ? deg[i] : 0;
  sm[threadIdx.x] = v;
  __syncthreads();
  for (int off = 1; off < 256; off <<= 1) {
    int t = (threadIdx.x >= off) ? sm[threadIdx.x - off] : 0;
    __syncthreads();
    sm[threadIdx.x] += t;
    __syncthreads();
  }
  if (i < n) rp[i + 1] = sm[threadIdx.x];
  if (threadIdx.x == 255) blksum[blockIdx.x] = sm[255];
}

__global__ void k_scan_top(int* __restrict__ blk, int nblk) {
  __shared__ int sm[256];
  int v = (threadIdx.x < nblk) ? blk[threadIdx.x] : 0;
  sm[threadIdx.x] = v;
  __syncthreads();
  for (int off = 1; off < 256; off <<= 1) {
    int t = (threadIdx.x >= off) ? sm[threadIdx.x - off] : 0;
    __syncthreads();
    sm[threadIdx.x] += t;
    __syncthreads();
  }
  if (threadIdx.x < nblk) blk[threadIdx.x] = sm[threadIdx.x] - v;
}

__global__ void k_scan_add(int* __restrict__ rp, const int* __restrict__ blk, int n) {
  int i = blockIdx.x * 256 + threadIdx.x;
  if (i == 0) rp[0] = 0;
  if (i < n) rp[i + 1] += blk[i >> 8];
}

__global__ void k_fill(const int* __restrict__ row, const int* __restrict__ col,
                       const int* __restrict__ deg, const int* __restrict__ rp,
                       int* __restrict__ cur, int2* __restrict__ cw, int e) {
  int i = blockIdx.x * 256 + threadIdx.x;
  if (i < e) {
    int r = row[i], c = col[i];
    int pos = rp[r] + atomicAdd(&cur[r], 1);
    int dc = deg[c];
    float w = (dc > 0) ? -rsqrtf((float)deg[r]) * rsqrtf((float)dc) : 0.0f;
    cw[pos] = make_int2(c, __float_as_int(w));
  }
}

__global__ void k_drop(const float* __restrict__ x, float* __restrict__ y,
                       uint32_t k0, uint32_t k1, int n) {
  int i = blockIdx.x * 256 + threadIdx.x;
  if (i < n) y[i] = drop_keep(k0, k1, (uint32_t)i) ? x[i] * 2.5f : 0.0f;
}

// Fused conv. Block = 256 threads = 4 waves, ROWS = 1024/COUT rows.
// Phase 1: per-wave CSR gather (16-deep batched) of Tx1 = L_hat @ xd; writes
//          x and Tx1 TRANSPOSED into T[128][ROWS(padded)].
// Phase 2: register-blocked MLP: each thread owns 4 rows x 1 out col; per k:
//          1 ds_read_b128 broadcast (4 row vals) + 1 ds_read_b32 (W) + 4 FMA,
//          fully unrolled (immediate LDS offsets). relu/dropout/store fused.
template<int COUT, bool RELU, bool DROPN>
__global__ __launch_bounds__(256) void k_conv(
    const float* __restrict__ xd, const int* __restrict__ rp,
    const int2* __restrict__ cw, const float* __restrict__ W,
    const float* __restrict__ b, float* __restrict__ out,
    uint32_t nk0, uint32_t nk1, int n) {
  constexpr int ROWS = 1024 / COUT;              // 16 (COUT=64) or 32 (COUT=32)
  constexpr int RPW  = ROWS / 4;                 // rows per wave: 4 or 8
  constexpr int TS   = (ROWS == 16) ? 20 : 36;   // padded stride (x4 aligned)
  __shared__ float Ws[128 * COUT];
  __shared__ __align__(16) float T[128][TS];

  // stage W (float4 coalesced)
  for (int i = threadIdx.x; i < 128 * COUT / 4; i += 256)
    ((float4*)Ws)[i] = ((const float4*)W)[i];

  const int row0 = blockIdx.x * ROWS;
  const int wave = threadIdx.x >> 6;
  const int t    = threadIdx.x & 63;

  for (int i = 0; i < RPW; ++i) {
    const int rl = wave * RPW + i;
    const int r  = row0 + rl;
    if (r < n) {
      float xv0 = xd[(size_t)r * 64 + t];
      float acc = 0.0f;
      const int ee0 = rp[r];
      const int e1  = rp[r + 1];
      for (int ee = ee0; ee < e1; ee += 16) {
        int   c[16];
        float w[16];
        #pragma unroll
        for (int j = 0; j < 16; ++j) {
          int idx = ee + j;
          int2 v = cw[idx < e1 ? idx : ee0];   // masked lanes re-read first edge
          c[j] = v.x;
          w[j] = (idx < e1) ? __int_as_float(v.y) : 0.0f;
        }
        float xv[16];
        #pragma unroll
        for (int j = 0; j < 16; ++j) xv[j] = xd[(size_t)c[j] * 64 + t];
        #pragma unroll
        for (int j = 0; j < 16; ++j) acc = fmaf(w[j], xv[j], acc);
      }
      T[t][rl]      = xv0;
      T[64 + t][rl] = acc;
    }
  }
  __syncthreads();

  const int o  = t & (COUT - 1);
  const int r0 = wave * RPW + ((COUT == 32) ? ((t >> 5) * 4) : 0);
  float a0 = b[o], a1 = a0, a2 = a0, a3 = a0;
  #pragma unroll
  for (int k = 0; k < 128; ++k) {
    const float4 xv = *reinterpret_cast<const float4*>(&T[k][r0]);
    const float  wv = Ws[k * COUT + o];
    a0 = fmaf(xv.x, wv, a0);
    a1 = fmaf(xv.y, wv, a1);
    a2 = fmaf(xv.z, wv, a2);
    a3 = fmaf(xv.w, wv, a3);
  }
  float a[4] = {a0, a1, a2, a3};
  #pragma unroll
  for (int i = 0; i < 4; ++i) {
    const int rr = row0 + r0 + i;
    if (rr < n) {
      float v = a[i];
      if (RELU) v = fmaxf(v, 0.0f);
      if (DROPN) {
        if (drop_keep(nk0, nk1, (uint32_t)(rr * 64 + o))) v *= 2.5f;
        else v = 0.0f;
      }
      out[(size_t)rr * COUT + o] = v;
    }
  }
}

extern "C" void kernel_launch(void* const* d_in, const int* in_sizes, int n_in,
                              void* d_out, int out_size, void* d_ws, size_t ws_size,
                              hipStream_t stream) {
  const float* x   = (const float*)d_in[0];
  const int*   ei  = (const int*)d_in[1];
  const float* W0  = (const float*)d_in[2];
  const float* b0  = (const float*)d_in[3];
  const float* W1f = (const float*)d_in[4];
  const float* b1  = (const float*)d_in[5];
  const float* W2  = (const float*)d_in[6];
  const float* b2  = (const float*)d_in[7];
  float* out = (float*)d_out;

  const int n = in_sizes[0] / 64;   // 50000
  const int e = in_sizes[1] / 2;    // 800000
  const int* row = ei;
  const int* col = ei + e;

  size_t off = 0;
  auto carve = [&](size_t elems) {
    size_t o = off;
    off += (elems + 255) & ~(size_t)255;
    return o;
  };
  int* base = (int*)d_ws;
  int*   deg = base + carve(n);
  int*   rp  = base + carve((size_t)n + 1);
  int*   cur = base + carve(n);
  int*   blk = base + carve(256);
  int2*  cw  = (int2*)(base + carve((size_t)e * 2));
  float* xa  = (float*)(base + carve((size_t)n * 64));
  float* xb  = (float*)(base + carve((size_t)n * 64));
  (void)ws_size;

  // dropout keys: fold_in(jax.random.key(1), i) = threefry2x32([0,1],[0,i])
  uint32_t dk[3][2];
  for (uint32_t i = 0; i < 3; ++i) tf2x32(0u, 1u, 0u, i, &dk[i][0], &dk[i][1]);

  hipMemsetAsync(deg, 0, (size_t)n * 4, stream);
  hipMemsetAsync(cur, 0, (size_t)n * 4, stream);

  const int be = (e + 255) / 256;
  const int bn = (n + 255) / 256;
  const int bd = ((n * 64) + 255) / 256;
  const int bc64 = (n + 15) / 16;   // 3125
  const int bc32 = (n + 31) / 32;   // 1563

  k_deg<<<be, 256, 0, stream>>>(row, deg, e);
  k_scan_block<<<bn, 256, 0, stream>>>(deg, rp, blk, n);
  k_scan_top<<<1, 256, 0, stream>>>(blk, bn);
  k_scan_add<<<bn, 256, 0, stream>>>(rp, blk, n);
  k_fill<<<be, 256, 0, stream>>>(row, col, deg, rp, cur, cw, e);

  k_drop<<<bd, 256, 0, stream>>>(x, xa, dk[0][0], dk[0][1], n * 64);
  k_conv<64, true,  true ><<<bc64, 256, 0, stream>>>(xa, rp, cw, W0,  b0, xb, dk[1][0], dk[1][1], n);
  k_conv<64, true,  true ><<<bc64, 256, 0, stream>>>(xb, rp, cw, W1f, b1, xa, dk[2][0], dk[2][1], n);
  k_conv<32, false, false><<<bc32, 256, 0, stream>>>(xa, rp, cw, W2,  b2, out, 0u, 0u, n);
}

// Round 4
// 357.419 us; speedup vs baseline: 3.8758x; 3.8758x over previous
//
#include <hip/hip_runtime.h>
#include <stdint.h>

__host__ __device__ inline void tf2x32(uint32_t k0, uint32_t k1,
                                       uint32_t x0, uint32_t x1,
                                       uint32_t* o0, uint32_t* o1) {
  const uint32_t ks2 = k0 ^ k1 ^ 0x1BD11BDAu;
#define ROTL(v, s) (((v) << (s)) | ((v) >> (32 - (s))))
#define RND(r) do { x0 += x1; x1 = ROTL(x1, r); x1 ^= x0; } while (0)
  x0 += k0; x1 += k1;
  RND(13); RND(15); RND(26); RND(6);
  x0 += k1; x1 += ks2 + 1u;
  RND(17); RND(29); RND(16); RND(24);
  x0 += ks2; x1 += k0 + 2u;
  RND(13); RND(15); RND(26); RND(6);
  x0 += k0; x1 += k1 + 3u;
  RND(17); RND(29); RND(16); RND(24);
  x0 += k1; x1 += ks2 + 4u;
  RND(13); RND(15); RND(26); RND(6);
  x0 += ks2; x1 += k0 + 5u;
  *o0 = x0; *o1 = x1;
#undef RND
#undef ROTL
}

__device__ inline bool drop_keep(uint32_t k0, uint32_t k1, uint32_t idx) {
  uint32_t o0, o1;
  tf2x32(k0, k1, 0u, idx, &o0, &o1);
  uint32_t bits = o0 ^ o1;
  float u = __uint_as_float((bits >> 9) | 0x3f800000u) - 1.0f;
  return u < 0.4f;
}

__global__ void k_deg(const int* __restrict__ row, int* __restrict__ deg, int e) {
  int i = blockIdx.x * 256 + threadIdx.x;
  if (i < e) atomicAdd(&deg[row[i]], 1);
}

__global__ void k_scan_block(const int* __restrict__ deg, int* __restrict__ rp,
                             int* __restrict__ blksum, int n) {
  __shared__ int sm[256];
  int i = blockIdx.x * 256 + threadIdx.x;
  int v = (i < n) ? deg[i] : 0;
  sm[threadIdx.x] = v;
  __syncthreads();
  for (int off = 1; off < 256; off <<= 1) {
    int t = (threadIdx.x >= off) ? sm[threadIdx.x - off] : 0;
    __syncthreads();
    sm[threadIdx.x] += t;
    __syncthreads();
  }
  if (i < n) rp[i + 1] = sm[threadIdx.x];
  if (threadIdx.x == 255) blksum[blockIdx.x] = sm[255];
}

__global__ void k_scan_top(int* __restrict__ blk, int nblk) {
  __shared__ int sm[256];
  int v = (threadIdx.x < nblk) ? blk[threadIdx.x] : 0;
  sm[threadIdx.x] = v;
  __syncthreads();
  for (int off = 1; off < 256; off <<= 1) {
    int t = (threadIdx.x >= off) ? sm[threadIdx.x - off] : 0;
    __syncthreads();
    sm[threadIdx.x] += t;
    __syncthreads();
  }
  if (threadIdx.x < nblk) blk[threadIdx.x] = sm[threadIdx.x] - v;
}

__global__ void k_scan_add(int* __restrict__ rp, const int* __restrict__ blk, int n) {
  int i = blockIdx.x * 256 + threadIdx.x;
  if (i == 0) rp[0] = 0;
  if (i < n) rp[i + 1] += blk[i >> 8];
}

__global__ void k_fill(const int* __restrict__ row, const int* __restrict__ col,
                       const int* __restrict__ deg, const int* __restrict__ rp,
                       int* __restrict__ cur, int2* __restrict__ cw, int e) {
  int i = blockIdx.x * 256 + threadIdx.x;
  if (i < e) {
    int r = row[i], c = col[i];
    int pos = rp[r] + atomicAdd(&cur[r], 1);
    int dc = deg[c];
    float w = (dc > 0) ? -rsqrtf((float)deg[r]) * rsqrtf((float)dc) : 0.0f;
    cw[pos] = make_int2(c, __float_as_int(w));
  }
}

__global__ void k_drop(const float* __restrict__ x, float* __restrict__ y,
                       uint32_t k0, uint32_t k1, int n) {
  int i = blockIdx.x * 256 + threadIdx.x;
  if (i < n) y[i] = drop_keep(k0, k1, (uint32_t)i) ? x[i] * 2.5f : 0.0f;
}

// Fused conv. Block = 256 threads = 4 waves, R = 16 rows.
// Phase 1 (gather, R2-proven): wave w handles rows 4w..4w+3; 8-deep batched
//   CSR gather of p = L_hat @ xd; writes x and p into xp[r][0:128] (row-major).
// Phase 2 (MLP, W-in-registers): thread (kc = tid/COUT, o = tid%COUT) holds
//   W[kc*CH .. kc*CH+CH)[o] in VGPRs (coalesced global load, amortized over
//   16 rows). Per row: CH/4 float4 broadcast LDS reads + CH FMAs -> partial.
// Phase 3: sum KC partials + bias + relu + next-layer dropout, coalesced store.
template<int COUT, bool RELU, bool DROPN>
__global__ __launch_bounds__(256, 4) void k_conv(
    const float* __restrict__ xd, const int* __restrict__ rp,
    const int2* __restrict__ cw, const float* __restrict__ W,
    const float* __restrict__ b, float* __restrict__ out,
    uint32_t nk0, uint32_t nk1, int n) {
  constexpr int R  = 16;
  constexpr int KC = (COUT == 64) ? 4 : 8;   // k-chunks
  constexpr int CH = 128 / KC;               // 32 or 16 k per chunk
  constexpr int TS = 132;                    // xp row stride (16B-aligned rows)
  __shared__ __align__(16) float xp[R][TS];
  __shared__ float partial[R * KC * COUT];   // 16 KB

  const int wave = threadIdx.x >> 6;
  const int t    = threadIdx.x & 63;
  const int row0 = blockIdx.x * R;

  // W column-chunk into registers (coalesced: consecutive o = consecutive addr)
  const int kc = threadIdx.x / COUT;
  const int o  = threadIdx.x % COUT;
  float Wreg[CH];
  #pragma unroll
  for (int j = 0; j < CH; ++j) Wreg[j] = W[(kc * CH + j) * COUT + o];

  // ---- Phase 1: gather (verbatim R2 inner loop, 8-deep) ----
  for (int i = 0; i < 4; ++i) {
    const int rl = wave * 4 + i;
    const int r  = row0 + rl;
    if (r < n) {
      float xv0 = xd[(size_t)r * 64 + t];
      float acc = 0.0f;
      const int ee0 = rp[r];
      const int e1  = rp[r + 1];
      for (int ee = ee0; ee < e1; ee += 8) {
        int   c[8];
        float w[8];
        #pragma unroll
        for (int j = 0; j < 8; ++j) {
          int idx = ee + j;
          int2 v = cw[idx < e1 ? idx : ee0];   // row nonempty here
          c[j] = v.x;
          w[j] = (idx < e1) ? __int_as_float(v.y) : 0.0f;
        }
        float xv[8];
        #pragma unroll
        for (int j = 0; j < 8; ++j) xv[j] = xd[(size_t)c[j] * 64 + t];
        #pragma unroll
        for (int j = 0; j < 8; ++j) acc = fmaf(w[j], xv[j], acc);
      }
      xp[rl][t]      = xv0;
      xp[rl][64 + t] = acc;
    }
  }
  __syncthreads();

  // ---- Phase 2: per-row partial dot (broadcast float4 reads, reg W) ----
  #pragma unroll 4
  for (int rl = 0; rl < R; ++rl) {
    float a = 0.0f;
    #pragma unroll
    for (int j4 = 0; j4 < CH; j4 += 4) {
      const float4 xv = *reinterpret_cast<const float4*>(&xp[rl][kc * CH + j4]);
      a = fmaf(xv.x, Wreg[j4 + 0], a);
      a = fmaf(xv.y, Wreg[j4 + 1], a);
      a = fmaf(xv.z, Wreg[j4 + 2], a);
      a = fmaf(xv.w, Wreg[j4 + 3], a);
    }
    partial[(rl * KC + kc) * COUT + o] = a;
  }
  __syncthreads();

  // ---- Phase 3: reduce + epilogue ----
  for (int i = threadIdx.x; i < R * COUT; i += 256) {
    const int rl = i / COUT;
    const int oo = i % COUT;
    const int rr = row0 + rl;
    if (rr < n) {
      float v = b[oo];
      #pragma unroll
      for (int k = 0; k < KC; ++k) v += partial[(rl * KC + k) * COUT + oo];
      if (RELU) v = fmaxf(v, 0.0f);
      if (DROPN) {
        if (drop_keep(nk0, nk1, (uint32_t)(rr * 64 + oo))) v *= 2.5f;
        else v = 0.0f;
      }
      out[(size_t)rr * COUT + oo] = v;
    }
  }
}

extern "C" void kernel_launch(void* const* d_in, const int* in_sizes, int n_in,
                              void* d_out, int out_size, void* d_ws, size_t ws_size,
                              hipStream_t stream) {
  const float* x   = (const float*)d_in[0];
  const int*   ei  = (const int*)d_in[1];
  const float* W0  = (const float*)d_in[2];
  const float* b0  = (const float*)d_in[3];
  const float* W1f = (const float*)d_in[4];
  const float* b1  = (const float*)d_in[5];
  const float* W2  = (const float*)d_in[6];
  const float* b2  = (const float*)d_in[7];
  float* out = (float*)d_out;

  const int n = in_sizes[0] / 64;   // 50000
  const int e = in_sizes[1] / 2;    // 800000
  const int* row = ei;
  const int* col = ei + e;

  size_t off = 0;
  auto carve = [&](size_t elems) {
    size_t o = off;
    off += (elems + 255) & ~(size_t)255;
    return o;
  };
  int* base = (int*)d_ws;
  int*   deg = base + carve(n);
  int*   rp  = base + carve((size_t)n + 1);
  int*   cur = base + carve(n);
  int*   blk = base + carve(256);
  int2*  cw  = (int2*)(base + carve((size_t)e * 2));
  float* xa  = (float*)(base + carve((size_t)n * 64));
  float* xb  = (float*)(base + carve((size_t)n * 64));
  (void)ws_size;

  // dropout keys: fold_in(jax.random.key(1), i) = threefry2x32([0,1],[0,i])
  uint32_t dk[3][2];
  for (uint32_t i = 0; i < 3; ++i) tf2x32(0u, 1u, 0u, i, &dk[i][0], &dk[i][1]);

  hipMemsetAsync(deg, 0, (size_t)n * 4, stream);
  hipMemsetAsync(cur, 0, (size_t)n * 4, stream);

  const int be = (e + 255) / 256;
  const int bn = (n + 255) / 256;
  const int bd = ((n * 64) + 255) / 256;
  const int bc = (n + 15) / 16;     // 3125 blocks, 16 rows each

  k_deg<<<be, 256, 0, stream>>>(row, deg, e);
  k_scan_block<<<bn, 256, 0, stream>>>(deg, rp, blk, n);
  k_scan_top<<<1, 256, 0, stream>>>(blk, bn);
  k_scan_add<<<bn, 256, 0, stream>>>(rp, blk, n);
  k_fill<<<be, 256, 0, stream>>>(row, col, deg, rp, cur, cw, e);

  k_drop<<<bd, 256, 0, stream>>>(x, xa, dk[0][0], dk[0][1], n * 64);
  k_conv<64, true,  true ><<<bc, 256, 0, stream>>>(xa, rp, cw, W0,  b0, xb, dk[1][0], dk[1][1], n);
  k_conv<64, true,  true ><<<bc, 256, 0, stream>>>(xb, rp, cw, W1f, b1, xa, dk[2][0], dk[2][1], n);
  k_conv<32, false, false><<<bc, 256, 0, stream>>>(xa, rp, cw, W2,  b2, out, 0u, 0u, n);
}